// Round 5
// baseline (374.059 us; speedup 1.0000x reference)
//
#include <hip/hip_runtime.h>

#define EPS 1e-6f
#define LN2F 0.69314718055994530942f
#define RPB 4   // rows per block

struct RunStats { int len, pre, suf, mx; };

__device__ inline RunStats rcombine(const RunStats& a, const RunStats& b) {
    RunStats r;
    r.len = a.len + b.len;
    r.pre = (a.pre == a.len) ? (a.len + b.pre) : a.pre;
    r.suf = (b.suf == b.len) ? (b.len + a.suf) : b.suf;
    r.mx  = max(max(a.mx, b.mx), a.suf + b.pre);
    return r;
}

// 2048 blocks x 256 threads; block handles 4 consecutive rows of N=4096.
// Wave w owns [w*1024, (w+1)*1024) of each row; lane loads float4 at +4*lane
// per 256-chunk (fully coalesced). Register double-buffer prefetches row r+1
// while consuming row r. The nibble transpose is INTRA-WAVE (each wave's own
// 64-dword LDS region), so there is NO __syncthreads in the row loop -- the
// only barrier (and its vmcnt(0) drain) is the final cross-wave combine.
__global__ __launch_bounds__(256, 4) void row_kernel(
        const float* __restrict__ yp, const float* __restrict__ yt,
        const float* __restrict__ dw,
        float* __restrict__ blk_wbce, int* __restrict__ blk_streak) {
    const int lane = threadIdx.x & 63;
    const int wave = threadIdx.x >> 6;
    const long base = (long)blockIdx.x * (RPB * 4096) + wave * 1024 + lane * 4;

    const float4* pp = (const float4*)(yp + base);
    const float4* tp = (const float4*)(yt + base);
    const float4* wp = (const float4*)(dw + base);
    // row r, chunk q -> float4 index r*1024 + q*64

    __shared__ unsigned nibbuf[256];      // 64 dwords per wave (private region)
    __shared__ RunStats sstat[RPB][4];
    __shared__ float ssum[4];

    float4 Pb[2][4], Tb[2][4], Wb[2][4];
    #pragma unroll
    for (int q = 0; q < 4; ++q) {         // prologue: row 0
        Pb[0][q] = pp[q * 64];
        Tb[0][q] = tp[q * 64];
        Wb[0][q] = wp[q * 64];
    }

    float sum = 0.0f;                     // w * log2(sel), all 4 rows
    #pragma unroll
    for (int r = 0; r < RPB; ++r) {
        const int cur = r & 1, nxt = cur ^ 1;
        if (r + 1 < RPB) {                // prefetch next row (independent)
            #pragma unroll
            for (int q = 0; q < 4; ++q) {
                Pb[nxt][q] = pp[(r + 1) * 1024 + q * 64];
                Tb[nxt][q] = tp[(r + 1) * 1024 + q * 64];
                Wb[nxt][q] = wp[(r + 1) * 1024 + q * 64];
            }
        }

        unsigned nibs = 0;                // byte q = correctness nibble chunk q
        #pragma unroll
        for (int q = 0; q < 4; ++q) {
            const float pv[4] = {Pb[cur][q].x, Pb[cur][q].y, Pb[cur][q].z, Pb[cur][q].w};
            const float tv[4] = {Tb[cur][q].x, Tb[cur][q].y, Tb[cur][q].z, Tb[cur][q].w};
            const float wv[4] = {Wb[cur][q].x, Wb[cur][q].y, Wb[cur][q].z, Wb[cur][q].w};
            #pragma unroll
            for (int c = 0; c < 4; ++c) {
                const bool tb = tv[c] != 0.0f;                 // y_true is 0/1
                const float sel = tb ? pv[c] : 1.0f - pv[c];
                sum = fmaf(wv[c], __log2f(sel + EPS), sum);
                const bool correct = (pv[c] > 0.5f) == tb;
                nibs |= (unsigned)correct << (8 * q + c);
            }
        }

        // intra-wave nibble transpose: no barrier needed (same-wave LDS RAW
        // is ordered by compiler-inserted lgkmcnt waits).
        nibbuf[wave * 64 + lane] = nibs;
        const uint4 d = *(const uint4*)&nibbuf[wave * 64 + 4 * (lane & 15)];
        const int qs = (lane >> 4) * 8;
        const unsigned mask = ((d.x >> qs) & 0xFu)
                            | (((d.y >> qs) & 0xFu) << 4)
                            | (((d.z >> qs) & 0xFu) << 8)
                            | (((d.w >> qs) & 0xFu) << 12);

        // per-lane stats over sequence-ordered 16-bit mask
        const int pre = __builtin_ctz(~mask);
        const int suf = __builtin_clz(~(mask << 16));
        int mx;
        {
            const unsigned p1 = mask;
            const unsigned p2 = p1 & (p1 << 1);
            const unsigned p4 = p2 & (p2 << 2);
            const unsigned p8 = p4 & (p4 << 4);
            unsigned z; int len;
            if (p8)      { z = p8; len = 8; }
            else if (p4) { z = p4; len = 4; }
            else if (p2) { z = p2; len = 2; }
            else         { z = p1; len = 1; }
            { const unsigned t = (z << 8) & p8; if (t) { z = t; len += 8; } }
            { const unsigned t = (z << 4) & p4; if (t) { z = t; len += 4; } }
            { const unsigned t = (z << 2) & p2; if (t) { z = t; len += 2; } }
            { const unsigned t = (z << 1) & p1; if (t) { z = t; len += 1; } }
            mx = mask ? len : 0;
        }

        // ordered wave tree: 5 packed 10-bit steps + 1 unpacked final step
        int packed = pre | (suf << 10) | (mx << 20);
        int alen = 16;
        #pragma unroll
        for (int off = 1; off < 32; off <<= 1) {
            const int o = __shfl_down(packed, off);
            const int apre = packed & 1023, asuf = (packed >> 10) & 1023, amx = packed >> 20;
            const int bpre = o & 1023,      bsuf = (o >> 10) & 1023,      bmx = o >> 20;
            const int npre = (apre == alen) ? (alen + bpre) : apre;
            const int nsuf = (bsuf == alen) ? (alen + asuf) : bsuf;
            const int nmx  = max(max(amx, bmx), asuf + bpre);
            packed = npre | (nsuf << 10) | (nmx << 20);
            alen <<= 1;
        }
        {   // final step: off = 32, alen = 512; lane 0 result valid
            const int o = __shfl_down(packed, 32);
            const int apre = packed & 1023, asuf = (packed >> 10) & 1023, amx = packed >> 20;
            const int bpre = o & 1023,      bsuf = (o >> 10) & 1023,      bmx = o >> 20;
            if (lane == 0) {
                RunStats g;
                g.len = 1024;
                g.pre = (apre == 512) ? (512 + bpre) : apre;
                g.suf = (bsuf == 512) ? (512 + asuf) : bsuf;
                g.mx  = max(max(amx, bmx), asuf + bpre);
                sstat[r][wave] = g;
            }
        }
    }

    // one wbce tree for all 4 rows
    #pragma unroll
    for (int off = 32; off; off >>= 1) sum += __shfl_down(sum, off);
    if (lane == 0) ssum[wave] = sum;

    __syncthreads();   // the block's only barrier
    if (threadIdx.x == 0) {
        int stot = 0;
        #pragma unroll
        for (int r = 0; r < RPB; ++r) {
            RunStats c = rcombine(rcombine(sstat[r][0], sstat[r][1]),
                                  rcombine(sstat[r][2], sstat[r][3]));
            stot += c.mx;
        }
        blk_wbce[blockIdx.x]   = -LN2F * (ssum[0] + ssum[1] + ssum[2] + ssum[3]);
        blk_streak[blockIdx.x] = stot;
    }
}

__global__ __launch_bounds__(1024) void finalize_kernel(
        const float* __restrict__ blk_wbce, const int* __restrict__ blk_streak,
        int nblk, int rows, float* __restrict__ out) {
    double s = 0.0;
    long long st = 0;
    for (int i = threadIdx.x; i < nblk; i += 1024) {
        s  += (double)blk_wbce[i];
        st += (long long)blk_streak[i];
    }
    __shared__ double sd[1024];
    __shared__ long long sl[1024];
    sd[threadIdx.x] = s; sl[threadIdx.x] = st;
    __syncthreads();
    for (int o = 512; o; o >>= 1) {
        if (threadIdx.x < o) {
            sd[threadIdx.x] += sd[threadIdx.x + o];
            sl[threadIdx.x] += sl[threadIdx.x + o];
        }
        __syncthreads();
    }
    if (threadIdx.x == 0) {
        const double total = (double)rows * 4096.0;
        const double wbce = sd[0] / total;
        const double cwl  = 1.0 - (double)sl[0] / total;
        out[0] = (float)(0.5 * wbce + 0.5 * cwl);
    }
}

extern "C" void kernel_launch(void* const* d_in, const int* in_sizes, int n_in,
                              void* d_out, int out_size, void* d_ws, size_t ws_size,
                              hipStream_t stream) {
    const float* yp = (const float*)d_in[0];
    const float* yt = (const float*)d_in[1];
    const float* dw = (const float*)d_in[2];
    float* out = (float*)d_out;

    const int rows = in_sizes[0] / 4096;   // 8192
    const int nblk = rows / RPB;           // 2048
    float* blk_wbce   = (float*)d_ws;
    int*   blk_streak = (int*)((char*)d_ws + (size_t)nblk * sizeof(float));

    row_kernel<<<nblk, 256, 0, stream>>>(yp, yt, dw, blk_wbce, blk_streak);
    finalize_kernel<<<1, 1024, 0, stream>>>(blk_wbce, blk_streak, nblk, rows, out);
}

// Round 6
// 353.497 us; speedup vs baseline: 1.0582x; 1.0582x over previous
//
#include <hip/hip_runtime.h>

#define EPS 1e-6f
#define LN2F 0.69314718055994530942f

// 2048 blocks x 256 threads; each WAVE owns one row of N=4096 (row = blk*4+wave).
// Row is processed in 16 chunks of 256 elements; lane loads float4 at
// chunk + 4*lane (fully coalesced, 1KB/instruction). 3-slot rolling prefetch
// keeps ~6 loads (96 cache lines) in flight per wave for its entire lifetime.
// Streak stats run on the SCALAR pipe from __ballot masks (wave-uniform SGPRs):
// online scan with cross-chunk carry -- zero VALU, zero LDS, zero barriers.
__global__ __launch_bounds__(256) void row_kernel(
        const float* __restrict__ yp, const float* __restrict__ yt,
        const float* __restrict__ dw,
        float* __restrict__ row_wbce, int* __restrict__ row_streak) {
    const int lane = threadIdx.x & 63;
    const int wave = threadIdx.x >> 6;
    const int row  = blockIdx.x * 4 + wave;
    const long base = (long)row * 4096 + lane * 4;

    const float4* pp = (const float4*)(yp + base);
    const float4* tp = (const float4*)(yt + base);
    const float4* wp = (const float4*)(dw + base);
    // chunk ch -> float4 index ch*64

    float4 P[3], T[3], W[3];
    #pragma unroll
    for (int k = 0; k < 3; ++k) {       // prologue: chunks 0..2 in flight
        P[k] = pp[k * 64];
        T[k] = tp[k * 64];
        W[k] = wp[k * 64];
    }

    float sum = 0.0f;    // w * log2(sel)
    int run = 0;         // current streak carried across chunks (scalar)
    int mxr = 0;         // max streak so far (scalar)

    #pragma unroll
    for (int ch = 0; ch < 16; ++ch) {
        const int s = ch % 3;
        const float4 p = P[s], t = T[s], w = W[s];
        if (ch + 3 < 16) {              // refill slot: keep queue full
            P[s] = pp[(ch + 3) * 64];
            T[s] = tp[(ch + 3) * 64];
            W[s] = wp[(ch + 3) * 64];
        }

        const float pv[4] = {p.x, p.y, p.z, p.w};
        const float tv[4] = {t.x, t.y, t.z, t.w};
        const float wv[4] = {w.x, w.y, w.z, w.w};
        unsigned long long B[4];        // ballot per component (wave-uniform)
        #pragma unroll
        for (int c = 0; c < 4; ++c) {
            const bool tb = tv[c] != 0.0f;                 // y_true is 0/1
            const float sel = tb ? pv[c] : 1.0f - pv[c];
            sum = fmaf(wv[c], __log2f(sel + EPS), sum);
            B[c] = __ballot((pv[c] > 0.5f) == tb);
        }

        // ---- scalar-pipe online streak scan (seq order: elem e=4i+c) ----
        const unsigned long long all = B[0] & B[1] & B[2] & B[3];
        if (all == ~0ULL) {
            run += 256;
            mxr = max(mxr, run);
        } else {
            // prefix run of chunk -> closes the carried run
            int pre = 1 << 30;
            #pragma unroll
            for (int c = 0; c < 4; ++c) {
                const unsigned long long z = ~B[c];
                if (z) pre = min(pre, 4 * (int)__builtin_ctzll(z) + c);
            }
            mxr = max(mxr, run + pre);
            // interior max run: iterate x &= (x << 1 in sequence space)
            unsigned long long x0 = B[0], x1 = B[1], x2 = B[2], x3 = B[3];
            int it = 0;
            while (x0 | x1 | x2 | x3) {
                ++it;
                const unsigned long long t3 = x3 << 1;
                x3 &= x2; x2 &= x1; x1 &= x0; x0 &= t3;
            }
            mxr = max(mxr, it);
            // suffix run of chunk -> new carry
            int last = -1;
            #pragma unroll
            for (int c = 0; c < 4; ++c) {
                const unsigned long long z = ~B[c];
                if (z) last = max(last, 4 * (63 - (int)__builtin_clzll(z)) + c);
            }
            run = 255 - last;
        }
    }
    mxr = max(mxr, run);   // row may end mid-run

    // wbce wave sum (commutative butterfly)
    #pragma unroll
    for (int off = 32; off; off >>= 1) sum += __shfl_down(sum, off);

    if (lane == 0) {
        row_wbce[row]   = -LN2F * sum;
        row_streak[row] = mxr;
    }
}

__global__ __launch_bounds__(1024) void finalize_kernel(
        const float* __restrict__ row_wbce, const int* __restrict__ row_streak,
        int rows, float* __restrict__ out) {
    double s = 0.0;
    long long st = 0;
    for (int i = threadIdx.x; i < rows; i += 1024) {
        s  += (double)row_wbce[i];
        st += (long long)row_streak[i];
    }
    __shared__ double sd[1024];
    __shared__ long long sl[1024];
    sd[threadIdx.x] = s; sl[threadIdx.x] = st;
    __syncthreads();
    for (int o = 512; o; o >>= 1) {
        if (threadIdx.x < o) {
            sd[threadIdx.x] += sd[threadIdx.x + o];
            sl[threadIdx.x] += sl[threadIdx.x + o];
        }
        __syncthreads();
    }
    if (threadIdx.x == 0) {
        const double total = (double)rows * 4096.0;
        const double wbce = sd[0] / total;
        const double cwl  = 1.0 - (double)sl[0] / total;
        out[0] = (float)(0.5 * wbce + 0.5 * cwl);
    }
}

extern "C" void kernel_launch(void* const* d_in, const int* in_sizes, int n_in,
                              void* d_out, int out_size, void* d_ws, size_t ws_size,
                              hipStream_t stream) {
    const float* yp = (const float*)d_in[0];
    const float* yt = (const float*)d_in[1];
    const float* dw = (const float*)d_in[2];
    float* out = (float*)d_out;

    const int rows = in_sizes[0] / 4096;   // 8192
    float* row_wbce   = (float*)d_ws;
    int*   row_streak = (int*)((char*)d_ws + (size_t)rows * sizeof(float));

    row_kernel<<<rows / 4, 256, 0, stream>>>(yp, yt, dw, row_wbce, row_streak);
    finalize_kernel<<<1, 1024, 0, stream>>>(row_wbce, row_streak, rows, out);
}